// Round 7
// baseline (6088.710 us; speedup 1.0000x reference)
//
#include <hip/hip_runtime.h>
#include <hip/hip_bf16.h>

#define B_ 64
#define T_ 256
#define H_ 1024
#define NKK_ 40  // K/32 = 1280/32
#define NB_ 256  // grid size (flag gather reads 256 words; do not change)

typedef __attribute__((ext_vector_type(8))) short short8;
typedef __attribute__((ext_vector_type(4))) float float4_;
typedef unsigned long long u64;

static __device__ __forceinline__ ushort f2bf(float v) {
  __hip_bfloat16 b = __float2bfloat16(v);
  return *reinterpret_cast<ushort*>(&b);
}
static __device__ __forceinline__ float bf2f(ushort u) {
  unsigned int x = ((unsigned int)u) << 16;
  return __builtin_bit_cast(float, x);
}
static __device__ __forceinline__ float sigm(float v) { return 1.0f / (1.0f + __expf(-v)); }
static __device__ __forceinline__ float tanh_fast(float v) {
  float e = __expf(2.0f * v);
  return 1.0f - 2.0f / (e + 1.0f);  // inf-safe at both ends
}

// Xall[t][b][j] bf16: j even = x[b][j/2][t], j odd = y[b][j/2][t-1] (0 at t=0)
__global__ __launch_bounds__(256) void build_X(const float* __restrict__ x,
                                               const float* __restrict__ y,
                                               ushort* __restrict__ Xall) {
  __shared__ float xl[128][33];
  __shared__ float yl[128][33];
  int b = blockIdx.x >> 3;
  int t0 = (blockIdx.x & 7) * 32;
  int tid = threadIdx.x;
  for (int it = 0; it < 16; ++it) {
    int idx = it * 256 + tid;
    int s = idx >> 5, tt = idx & 31;
    xl[s][tt] = x[((size_t)b * 128 + s) * T_ + t0 + tt];
    int ty = t0 + tt - 1;
    yl[s][tt] = (ty >= 0) ? y[((size_t)b * 128 + s) * T_ + ty] : 0.0f;
  }
  __syncthreads();
  for (int tt = 0; tt < 32; ++tt) {
    float v = (tid & 1) ? yl[tid >> 1][tt] : xl[tid >> 1][tt];
    Xall[((size_t)(t0 + tt) * B_ + b) * 256 + tid] = f2bf(v);
  }
}

// Bp[(nb*40+kk)*64 + l][8]: lane l supplies B[k=32kk+8*(l>>4)+j][localcol=l&15]
// localcol q -> gate g=q>>2, hcol m=q&3; col = nb*4+m of gate g's W
__global__ __launch_bounds__(256) void prep_weights(const float* __restrict__ Wf,
                                                    const float* __restrict__ Wi,
                                                    const float* __restrict__ Wu,
                                                    const float* __restrict__ Wo,
                                                    ushort* __restrict__ Bp) {
  int flat = blockIdx.x * 256 + threadIdx.x;
  int l = flat & 63;
  int g2 = flat >> 6;
  int kk = g2 % NKK_;
  int nb = g2 / NKK_;
  int q = l & 15, kg = l >> 4;
  int g = q >> 2, m = q & 3;
  const float* W = (g == 0) ? Wf : (g == 1) ? Wi : (g == 2) ? Wu : Wo;
  int col = nb * 4 + m;
  ushort tmp[8];
#pragma unroll
  for (int j = 0; j < 8; ++j) {
    int k = kk * 32 + kg * 8 + j;
    tmp[j] = f2bf(W[(size_t)k * H_ + col]);
  }
  *(short8*)(Bp + (size_t)flat * 8) = *(short8*)tmp;
}

// Persistent LSTM. Hh is COLUMN-major [slot][hcol][b] so producer writes are
// 4x128B contiguous (8 lines/block/step). Consumers stage the slot through
// LDS (coalesced 16B/lane agent loads + bank-swizzled transpose), then read
// MFMA A-fragments as 16B LDS vectors.
__global__ __launch_bounds__(1024) void lstm_persist(
    const ushort* __restrict__ Xall, const ushort* __restrict__ Bp,
    const float* __restrict__ bfp, const float* __restrict__ bip,
    const float* __restrict__ bup, const float* __restrict__ bop,
    ushort* __restrict__ Hh, float* __restrict__ out,
    unsigned int* __restrict__ flags) {
  __shared__ ushort stg[4][64][256];     // 128 KB  [kq][b][lc ^ ((b&7)<<3)]
  __shared__ float gbuf[4][4][16][17];   // 17 KB   K-split partials
  __shared__ ushort hbuf[4][64][18];     // 9 KB    out-burst (16 steps, bf16)
  __shared__ ushort hx[4][64];           // 0.5 KB  current h, bf16
  const int tid = threadIdx.x;
  const int w = tid >> 6, l = tid & 63;
  const int mt = w & 3, kq = w >> 2;
  const int ar = l & 15, kg = l >> 4;
  const int bA = mt * 16 + ar;
  const int nb = blockIdx.x;

  // K-slice map: wave kq owns x-slices {2kq,2kq+1}, h-slices {8kq..8kq+7}
  short8 bfrag[10];
  {
    const ushort* bp0 = Bp + ((size_t)nb * NKK_ * 64 + l) * 8;
#pragma unroll
    for (int u = 0; u < 2; ++u)
      bfrag[u] = *(const short8*)(bp0 + (size_t)(2 * kq + u) * 64 * 8);
#pragma unroll
    for (int u = 2; u < 10; ++u)
      bfrag[u] = *(const short8*)(bp0 + (size_t)(8 + 8 * kq + (u - 2)) * 64 * 8);
  }
#pragma unroll
  for (int u = 0; u < 10; ++u) asm volatile("" : "+v"(bfrag[u]));

  const int bb = tid & 63, m = (tid >> 6) & 3;
  const int hcol = nb * 4 + m;
  float biasF = 0, biasI = 0, biasU = 0, biasO = 0, creg = 0;
  if (tid < 256) {
    biasF = bfp[hcol]; biasI = bip[hcol]; biasU = bup[hcol]; biasO = bop[hcol];
  }

  for (int t = 0; t < T_; ++t) {
    // ---- x-part: 2 MFMAs, barrier-independent ----
    const ushort* xrow = Xall + ((size_t)t * B_ + bA) * 256 + kg * 8;
    float4_ acc = {0.f, 0.f, 0.f, 0.f};
#pragma unroll
    for (int u = 0; u < 2; ++u) {
      short8 av = *(const short8*)(xrow + (2 * kq + u) * 32);
      acc = __builtin_amdgcn_mfma_f32_16x16x32_bf16(av, bfrag[u], acc, 0, 0, 0);
    }
    // ---- wait for h(t): wave0 gathers 256 flags (4 indep loads/lane) ----
    if (t > 0 && tid < 64) {
      unsigned int tgt = (unsigned int)t;
      for (;;) {
        unsigned int f0 = __hip_atomic_load(&flags[l * 4 + 0], __ATOMIC_RELAXED,
                                            __HIP_MEMORY_SCOPE_AGENT);
        unsigned int f1 = __hip_atomic_load(&flags[l * 4 + 1], __ATOMIC_RELAXED,
                                            __HIP_MEMORY_SCOPE_AGENT);
        unsigned int f2 = __hip_atomic_load(&flags[l * 4 + 2], __ATOMIC_RELAXED,
                                            __HIP_MEMORY_SCOPE_AGENT);
        unsigned int f3 = __hip_atomic_load(&flags[l * 4 + 3], __ATOMIC_RELAXED,
                                            __HIP_MEMORY_SCOPE_AGENT);
        bool ok = (f0 >= tgt) & (f1 >= tgt) & (f2 >= tgt) & (f3 >= tgt);
        if (__all(ok)) break;
        __builtin_amdgcn_s_sleep(1);
      }
      asm volatile("" ::: "memory");
    }
    __syncthreads();
    // ---- stage h(t) slot -> LDS (coalesced loads, swizzled transpose) ----
    {
      const ushort* hsrc = Hh + (size_t)(t & 1) * H_ * B_;
      const int b0 = 8 * (l & 7);
#pragma unroll
      for (int it = 0; it < 8; ++it) {
        int lc = mt * 64 + it * 8 + (l >> 3);              // local hcol in region kq
        const u64* p = (const u64*)(hsrc + ((size_t)(kq * 256 + lc)) * 64 + b0);
        union { u64 q[2]; ushort us[8]; } cv;
        cv.q[0] = __hip_atomic_load(p, __ATOMIC_RELAXED, __HIP_MEMORY_SCOPE_AGENT);
        cv.q[1] = __hip_atomic_load(p + 1, __ATOMIC_RELAXED, __HIP_MEMORY_SCOPE_AGENT);
#pragma unroll
        for (int jj = 0; jj < 8; ++jj) {
          int j = (jj + (l >> 3)) & 7;                     // rotate for bank spread
          int b = b0 + j;
          stg[kq][b][lc ^ ((b & 7) << 3)] = cv.us[j];
        }
      }
    }
    __syncthreads();
    // ---- h-part: 8 MFMAs from swizzled LDS ----
    {
      const int sw = (bA & 7) << 3;
#pragma unroll
      for (int u = 2; u < 10; ++u) {
        int lc0 = (u - 2) * 32 + kg * 8;
        short8 av = *(const short8*)&stg[kq][bA][lc0 ^ sw];
        acc = __builtin_amdgcn_mfma_f32_16x16x32_bf16(av, bfrag[u], acc, 0, 0, 0);
      }
    }
    {
      int rbase = kg * 4;
#pragma unroll
      for (int r = 0; r < 4; ++r) gbuf[kq][mt][rbase + r][ar] = acc[r];
    }
    __syncthreads();
    if (tid < 256) {
      int row = bb & 15, mtt = bb >> 4;
      float f = 0, i = 0, uu = 0, o = 0;
#pragma unroll
      for (int k2 = 0; k2 < 4; ++k2) {
        f  += gbuf[k2][mtt][row][m];
        i  += gbuf[k2][mtt][row][4 + m];
        uu += gbuf[k2][mtt][row][8 + m];
        o  += gbuf[k2][mtt][row][12 + m];
      }
      f += biasF; i += biasI; uu += biasU; o += biasO;
      creg = fmaf(creg, sigm(f), sigm(i) * tanh_fast(uu));
      float h = sigm(o) * tanh_fast(creg);
      ushort hv = f2bf(h);
      hx[m][bb] = hv;
      hbuf[m][bb][t & 15] = hv;
      if ((t & 15) == 15) {  // 64 B line-exact burst per thread
        float* orow = out + ((size_t)bb * H_ + hcol) * T_ + (t - 15);
#pragma unroll
        for (int tt = 0; tt < 16; tt += 4) {
          float4 v = {bf2f(hbuf[m][bb][tt]), bf2f(hbuf[m][bb][tt + 1]),
                      bf2f(hbuf[m][bb][tt + 2]), bf2f(hbuf[m][bb][tt + 3])};
          *(float4*)(orow + tt) = v;
        }
      }
    }
    __syncthreads();  // hx complete; gbuf free
    // ---- col-major h store: 4 rows x 128 B, wave0 lanes 0..31 ----
    if (tid < 32) {
      int ms = l >> 3, bs = 8 * (l & 7);
      const u64* src = (const u64*)&hx[ms][bs];
      u64 q0 = src[0], q1 = src[1];
      u64* dst = (u64*)(Hh + (size_t)((t + 1) & 1) * H_ * B_ +
                        ((size_t)(nb * 4 + ms)) * 64 + bs);
      __hip_atomic_store(dst, q0, __ATOMIC_RELAXED, __HIP_MEMORY_SCOPE_AGENT);
      __hip_atomic_store(dst + 1, q1, __ATOMIC_RELAXED, __HIP_MEMORY_SCOPE_AGENT);
    }
    asm volatile("s_waitcnt vmcnt(0)" ::: "memory");
    if (tid == 0)
      __hip_atomic_store(&flags[nb], (unsigned int)(t + 1), __ATOMIC_RELAXED,
                         __HIP_MEMORY_SCOPE_AGENT);
  }
  // ---- final c, coalesced via LDS transpose (reuse gbuf) ----
  __syncthreads();
  float* cw = &gbuf[0][0][0][0];
  if (tid < 256) cw[bb * 4 + m] = creg;
  __syncthreads();
  if (tid < 64) {
    float4 v = *(float4*)&cw[l * 4];
    *(float4*)(out + (size_t)B_ * H_ * T_ + (size_t)l * H_ + nb * 4) = v;
  }
}

extern "C" void kernel_launch(void* const* d_in, const int* in_sizes, int n_in,
                              void* d_out, int out_size, void* d_ws, size_t ws_size,
                              hipStream_t stream) {
  const float* x  = (const float*)d_in[0];
  const float* y  = (const float*)d_in[2];
  const float* Wf = (const float*)d_in[3];  const float* bf = (const float*)d_in[4];
  const float* Wi = (const float*)d_in[5];  const float* bi = (const float*)d_in[6];
  const float* Wu = (const float*)d_in[7];  const float* bu = (const float*)d_in[8];
  const float* Wo = (const float*)d_in[9];  const float* bo = (const float*)d_in[10];
  float* out = (float*)d_out;

  char* p = (char*)d_ws;
  ushort* Bp = (ushort*)p;        p += (size_t)256 * NKK_ * 64 * 8 * 2;  // 10.49 MB
  ushort* Xall = (ushort*)p;      p += (size_t)T_ * B_ * 256 * 2;        // 8.39 MB
  unsigned int* flags = (unsigned int*)p; p += 4096;                     // 256 words
  ushort* Hh = (ushort*)p;        // 2 slots x [hcol][b] = 2 x 128 KB

  prep_weights<<<(256 * NKK_ * 64) / 256, 256, 0, stream>>>(Wf, Wi, Wu, Wo, Bp);
  build_X<<<B_ * 8, 256, 0, stream>>>(x, y, Xall);
  (void)hipMemsetAsync(flags, 0, 4096, stream);
  (void)hipMemsetAsync(Hh, 0, (size_t)B_ * H_ * 2, stream);  // slot 0 = h_{-1} = 0

  lstm_persist<<<NB_, 1024, 0, stream>>>(Xall, Bp, bf, bi, bu, bo, Hh, out, flags);
}

// Round 8
// 2498.669 us; speedup vs baseline: 2.4368x; 2.4368x over previous
//
#include <hip/hip_runtime.h>
#include <hip/hip_bf16.h>

#define B_ 64
#define T_ 256
#define H_ 1024
#define NKK_ 40  // K/32 = 1280/32
#define NB_ 256  // grid size (flag gather reads 256 words; do not change)

typedef __attribute__((ext_vector_type(8))) short short8;
typedef __attribute__((ext_vector_type(4))) float float4_;
typedef unsigned long long u64;

static __device__ __forceinline__ ushort f2bf(float v) {
  __hip_bfloat16 b = __float2bfloat16(v);
  return *reinterpret_cast<ushort*>(&b);
}
static __device__ __forceinline__ float bf2f(ushort u) {
  unsigned int x = ((unsigned int)u) << 16;
  return __builtin_bit_cast(float, x);
}
static __device__ __forceinline__ float sigm(float v) { return 1.0f / (1.0f + __expf(-v)); }
static __device__ __forceinline__ float tanh_fast(float v) {
  float e = __expf(2.0f * v);
  return 1.0f - 2.0f / (e + 1.0f);  // inf-safe at both ends
}

// Xall[t][b][j] bf16: j even = x[b][j/2][t], j odd = y[b][j/2][t-1] (0 at t=0)
__global__ __launch_bounds__(256) void build_X(const float* __restrict__ x,
                                               const float* __restrict__ y,
                                               ushort* __restrict__ Xall) {
  __shared__ float xl[128][33];
  __shared__ float yl[128][33];
  int b = blockIdx.x >> 3;
  int t0 = (blockIdx.x & 7) * 32;
  int tid = threadIdx.x;
  for (int it = 0; it < 16; ++it) {
    int idx = it * 256 + tid;
    int s = idx >> 5, tt = idx & 31;
    xl[s][tt] = x[((size_t)b * 128 + s) * T_ + t0 + tt];
    int ty = t0 + tt - 1;
    yl[s][tt] = (ty >= 0) ? y[((size_t)b * 128 + s) * T_ + ty] : 0.0f;
  }
  __syncthreads();
  for (int tt = 0; tt < 32; ++tt) {
    float v = (tid & 1) ? yl[tid >> 1][tt] : xl[tid >> 1][tt];
    Xall[((size_t)(t0 + tt) * B_ + b) * 256 + tid] = f2bf(v);
  }
}

// Bp[(nb*40+kk)*64 + l][8]: lane l supplies B[k=32kk+8*(l>>4)+j][localcol=l&15]
// localcol q -> gate g=q>>2, hcol m=q&3; col = nb*4+m of gate g's W
__global__ __launch_bounds__(256) void prep_weights(const float* __restrict__ Wf,
                                                    const float* __restrict__ Wi,
                                                    const float* __restrict__ Wu,
                                                    const float* __restrict__ Wo,
                                                    ushort* __restrict__ Bp) {
  int flat = blockIdx.x * 256 + threadIdx.x;
  int l = flat & 63;
  int g2 = flat >> 6;
  int kk = g2 % NKK_;
  int nb = g2 / NKK_;
  int q = l & 15, kg = l >> 4;
  int g = q >> 2, m = q & 3;
  const float* W = (g == 0) ? Wf : (g == 1) ? Wi : (g == 2) ? Wu : Wo;
  int col = nb * 4 + m;
  ushort tmp[8];
#pragma unroll
  for (int j = 0; j < 8; ++j) {
    int k = kk * 32 + kg * 8 + j;
    tmp[j] = f2bf(W[(size_t)k * H_ + col]);
  }
  *(short8*)(Bp + (size_t)flat * 8) = *(short8*)tmp;
}

// Persistent LSTM: 256 blocks x 1024 threads, whole T loop in-kernel.
// Hh row-major [slot][b][hcol]: reads are one 16B load/lane (L2-combined
// across the XCD). Writes: wave0 packs the block's 4 h-cols per batch row
// into one u64 -> 64 x 8B agent stores (vs 256 scattered 2B in round 5).
__global__ __launch_bounds__(1024) void lstm_persist(
    const ushort* __restrict__ Xall, const ushort* __restrict__ Bp,
    const float* __restrict__ bfp, const float* __restrict__ bip,
    const float* __restrict__ bup, const float* __restrict__ bop,
    ushort* __restrict__ Hh, float* __restrict__ out,
    unsigned int* __restrict__ flags) {
  __shared__ float gbuf[4][4][16][17];   // 17 KB  K-split partials
  __shared__ ushort hbuf[4][64][17];     // 8.5 KB out-burst (16 steps, bf16)
  __shared__ ushort hxT[64][4];          // 0.5 KB current h, [b][m] for packing
  const int tid = threadIdx.x;
  const int w = tid >> 6, l = tid & 63;
  const int mt = w & 3, kq = w >> 2;
  const int ar = l & 15, kg = l >> 4;
  const int bA = mt * 16 + ar;
  const int nb = blockIdx.x;

  // K-slice map: wave kq owns x-slices {2kq,2kq+1}, h-slices {8kq..8kq+7}
  short8 bfrag[10];
  {
    const ushort* bp0 = Bp + ((size_t)nb * NKK_ * 64 + l) * 8;
#pragma unroll
    for (int u = 0; u < 2; ++u)
      bfrag[u] = *(const short8*)(bp0 + (size_t)(2 * kq + u) * 64 * 8);
#pragma unroll
    for (int u = 2; u < 10; ++u)
      bfrag[u] = *(const short8*)(bp0 + (size_t)(8 + 8 * kq + (u - 2)) * 64 * 8);
  }
#pragma unroll
  for (int u = 0; u < 10; ++u) asm volatile("" : "+v"(bfrag[u]));

  const int bb = tid & 63, m = (tid >> 6) & 3;
  const int hcol = nb * 4 + m;
  float biasF = 0, biasI = 0, biasU = 0, biasO = 0, creg = 0;
  if (tid < 256) {
    biasF = bfp[hcol]; biasI = bip[hcol]; biasU = bup[hcol]; biasO = bop[hcol];
  }

  for (int t = 0; t < T_; ++t) {
    // ---- x-part: 2 MFMAs, barrier-independent ----
    const ushort* xrow = Xall + ((size_t)t * B_ + bA) * 256 + kg * 8;
    float4_ acc = {0.f, 0.f, 0.f, 0.f};
#pragma unroll
    for (int u = 0; u < 2; ++u) {
      short8 av = *(const short8*)(xrow + (2 * kq + u) * 32);
      acc = __builtin_amdgcn_mfma_f32_16x16x32_bf16(av, bfrag[u], acc, 0, 0, 0);
    }
    // ---- wait for h(t): wave0 gathers 256 flags (4 indep loads/lane) ----
    if (t > 0 && tid < 64) {
      unsigned int tgt = (unsigned int)t;
      for (;;) {
        unsigned int f0 = __hip_atomic_load(&flags[l * 4 + 0], __ATOMIC_RELAXED,
                                            __HIP_MEMORY_SCOPE_AGENT);
        unsigned int f1 = __hip_atomic_load(&flags[l * 4 + 1], __ATOMIC_RELAXED,
                                            __HIP_MEMORY_SCOPE_AGENT);
        unsigned int f2 = __hip_atomic_load(&flags[l * 4 + 2], __ATOMIC_RELAXED,
                                            __HIP_MEMORY_SCOPE_AGENT);
        unsigned int f3 = __hip_atomic_load(&flags[l * 4 + 3], __ATOMIC_RELAXED,
                                            __HIP_MEMORY_SCOPE_AGENT);
        bool ok = (f0 >= tgt) & (f1 >= tgt) & (f2 >= tgt) & (f3 >= tgt);
        if (__all(ok)) break;
        __builtin_amdgcn_s_sleep(1);
      }
      asm volatile("" ::: "memory");
    }
    __syncthreads();
    // ---- h-part: 8 MFMAs, per-lane 16B strided loads (L2-combined) ----
    const ushort* hrow = Hh + ((size_t)(t & 1) * B_ + bA) * H_ + kg * 8;
#pragma unroll
    for (int u = 2; u < 10; ++u) {
      const u64* p = (const u64*)(hrow + (8 * kq + (u - 2)) * 32);
      union { u64 q[2]; short8 s; } cv;
      cv.q[0] = __hip_atomic_load(p, __ATOMIC_RELAXED, __HIP_MEMORY_SCOPE_AGENT);
      cv.q[1] = __hip_atomic_load(p + 1, __ATOMIC_RELAXED, __HIP_MEMORY_SCOPE_AGENT);
      acc = __builtin_amdgcn_mfma_f32_16x16x32_bf16(cv.s, bfrag[u], acc, 0, 0, 0);
    }
    {
      int rbase = kg * 4;
#pragma unroll
      for (int r = 0; r < 4; ++r) gbuf[kq][mt][rbase + r][ar] = acc[r];
    }
    __syncthreads();
    if (tid < 256) {
      int row = bb & 15, mtt = bb >> 4;
      float f = 0, i = 0, uu = 0, o = 0;
#pragma unroll
      for (int k2 = 0; k2 < 4; ++k2) {
        f  += gbuf[k2][mtt][row][m];
        i  += gbuf[k2][mtt][row][4 + m];
        uu += gbuf[k2][mtt][row][8 + m];
        o  += gbuf[k2][mtt][row][12 + m];
      }
      f += biasF; i += biasI; uu += biasU; o += biasO;
      creg = fmaf(creg, sigm(f), sigm(i) * tanh_fast(uu));
      float h = sigm(o) * tanh_fast(creg);
      ushort hv = f2bf(h);
      hxT[bb][m] = hv;
      hbuf[m][bb][t & 15] = hv;
      if ((t & 15) == 15) {  // 64 B line-exact burst per thread
        float* orow = out + ((size_t)bb * H_ + hcol) * T_ + (t - 15);
#pragma unroll
        for (int tt = 0; tt < 16; tt += 4) {
          float4 v = {bf2f(hbuf[m][bb][tt]), bf2f(hbuf[m][bb][tt + 1]),
                      bf2f(hbuf[m][bb][tt + 2]), bf2f(hbuf[m][bb][tt + 3])};
          *(float4*)(orow + tt) = v;
        }
      }
    }
    __syncthreads();  // hxT complete
    // ---- h store: wave0, one packed 8B agent store per batch row ----
    if (tid < 64) {
      u64 q = *(const u64*)&hxT[l][0];  // 4 bf16 = this block's 4 h-cols
      u64* dst = (u64*)(Hh + ((size_t)((t + 1) & 1) * B_ + l) * H_ + nb * 4);
      __hip_atomic_store(dst, q, __ATOMIC_RELAXED, __HIP_MEMORY_SCOPE_AGENT);
    }
    asm volatile("s_waitcnt vmcnt(0)" ::: "memory");
    if (tid == 0)
      __hip_atomic_store(&flags[nb], (unsigned int)(t + 1), __ATOMIC_RELAXED,
                         __HIP_MEMORY_SCOPE_AGENT);
  }
  // ---- final c, coalesced via LDS transpose (reuse gbuf) ----
  __syncthreads();
  float* cw = &gbuf[0][0][0][0];
  if (tid < 256) cw[bb * 4 + m] = creg;
  __syncthreads();
  if (tid < 64) {
    float4 v = *(float4*)&cw[l * 4];
    *(float4*)(out + (size_t)B_ * H_ * T_ + (size_t)l * H_ + nb * 4) = v;
  }
}

extern "C" void kernel_launch(void* const* d_in, const int* in_sizes, int n_in,
                              void* d_out, int out_size, void* d_ws, size_t ws_size,
                              hipStream_t stream) {
  const float* x  = (const float*)d_in[0];
  const float* y  = (const float*)d_in[2];
  const float* Wf = (const float*)d_in[3];  const float* bf = (const float*)d_in[4];
  const float* Wi = (const float*)d_in[5];  const float* bi = (const float*)d_in[6];
  const float* Wu = (const float*)d_in[7];  const float* bu = (const float*)d_in[8];
  const float* Wo = (const float*)d_in[9];  const float* bo = (const float*)d_in[10];
  float* out = (float*)d_out;

  char* p = (char*)d_ws;
  ushort* Bp = (ushort*)p;        p += (size_t)256 * NKK_ * 64 * 8 * 2;  // 10.49 MB
  ushort* Xall = (ushort*)p;      p += (size_t)T_ * B_ * 256 * 2;        // 8.39 MB
  unsigned int* flags = (unsigned int*)p; p += 4096;                     // 256 words
  ushort* Hh = (ushort*)p;        // 2 slots x [b][hcol] = 2 x 128 KB

  prep_weights<<<(256 * NKK_ * 64) / 256, 256, 0, stream>>>(Wf, Wi, Wu, Wo, Bp);
  build_X<<<B_ * 8, 256, 0, stream>>>(x, y, Xall);
  (void)hipMemsetAsync(flags, 0, 4096, stream);
  (void)hipMemsetAsync(Hh, 0, (size_t)B_ * H_ * 2, stream);  // slot 0 = h_{-1} = 0

  lstm_persist<<<NB_, 1024, 0, stream>>>(Xall, Bp, bf, bi, bu, bo, Hh, out, flags);
}